// Round 5
// baseline (327.484 us; speedup 1.0000x reference)
//
#include <hip/hip_runtime.h>
#include <math.h>

#define LMAX 8
#define NCOEF 45   // (LMAX+1)*(LMAX+2)/2
#define NY 81      // (LMAX+1)^2

// Native clang vector: __builtin_nontemporal_store rejects HIP_vector_type.
typedef float f4 __attribute__((ext_vector_type(4)));

struct Coefs { float c[NCOEF]; };

// Slice layout per wave (floats), groups flushed together:
//   group A: l=1..4  bases 0,192,512,960   (widths 3,5,7,9  -> 1536 floats)
//   group B: l=5,6   bases 0,704           (widths 11,13    -> 1536 floats)
//   group C: l=7     base  0               (width 15)
//   group D: l=8     base  0               (width 17)
// Slice = 1536 floats = 6 KB/wave -> 24 KB/block -> 6 blocks/CU fits 160 KB.
#define SLICE 1536

__global__ __launch_bounds__(256, 6) void sph_kernel(const float* __restrict__ R,
                                                     float* __restrict__ out,
                                                     int N, Coefs cf) {
    __shared__ __align__(16) float lds[4][SLICE];

    const int tid  = threadIdx.x;
    const int wave = tid >> 6;
    const int lane = tid & 63;
    const int i    = blockIdx.x * 256 + tid;
    const int wave_base = blockIdx.x * 256 + wave * 64;

    // Load direction (safe defaults for out-of-range lanes: unit z).
    float x = 0.0f, y = 0.0f, z = 1.0f;
    if (i < N) {
        x = R[3 * i + 0];
        y = R[3 * i + 1];
        z = R[3 * i + 2];
    }
    float rinv = 1.0f / sqrtf(x * x + y * y + z * z);
    x *= rinv; y *= rinv; z *= rinv;

    int cnt = N - wave_base;
    if (cnt > 64) cnt = 64;
    if (cnt < 0)  cnt = 0;

    float* sl = &lds[wave][0];

    // l=0: Y00 is a direction-independent constant; column 0 is per-point
    // contiguous -> direct coalesced store, no LDS round-trip.
    if (i < N) __builtin_nontemporal_store(cf.c[0], &out[i]);

    // Per-l sub-block base within the slice (floats).
    const int GBASE[9] = {0, 0, 192, 512, 960, 0, 704, 0, 0};

    // l-outer recurrence ladders: per-m state only; values written through
    // to LDS as produced (no band[] array).
    float A[LMAX + 1], B[LMAX + 1], P1[LMAX + 1], P2[LMAX + 1];
    A[0] = 1.0f; B[0] = 0.0f;
    P1[0] = 1.0f; P2[0] = 0.0f;   // l=0 band already emitted (p00 = 1)

    #pragma unroll
    for (int l = 1; l <= LMAX; ++l) {
        A[l] = x * A[l - 1] - y * B[l - 1];
        B[l] = x * B[l - 1] + y * A[l - 1];

        const int w = 2 * l + 1;
        float* slr = sl + GBASE[l] + lane * w;   // odd stride: conflict-free

        #pragma unroll
        for (int m = 0; m <= l; ++m) {
            float p;
            if (m == l) {
                float pmm = 1.0f;                      // (2l-1)!! at compile time
                #pragma unroll
                for (int k = 1; k < 2 * l; k += 2) pmm *= (float)k;
                p = pmm;
                P2[m] = 0.0f;
            } else if (m == l - 1) {
                p = (2.0f * (float)l - 1.0f) * z * P1[m];
                P2[m] = P1[m];
            } else {
                float o1 = P1[m];
                p = ((2.0f * (float)l - 1.0f) * z * o1 - (float)(l + m - 1) * P2[m])
                    * (1.0f / (float)(l - m));         // folds to constant
                P2[m] = o1;
            }
            P1[m] = p;
            float np = cf.c[l * (l + 1) / 2 + m] * p;  // constant index
            if (m == 0) {
                slr[l] = np;
            } else {
                slr[l + m] = np * A[m];
                slr[l - m] = np * B[m];
            }
        }

        // Flush at group boundaries: one LDS RAW wait per GROUP (4/wave)
        // instead of per l (8/wave). All offsets compile-time after unroll.
        const bool flush_now = (l == 4) || (l == 6) || (l == 7) || (l == 8);
        if (flush_now) {
            const int lo = (l == 4) ? 1 : (l == 6) ? 5 : l;
            #pragma unroll
            for (int fl = 1; fl <= LMAX; ++fl) {
                if (fl < lo || fl > l) continue;       // folds away
                const int fw = 2 * fl + 1;
                const float* fs = sl + GBASE[fl];
                const size_t region = (size_t)N * (size_t)(fl * fl)
                                    + (size_t)wave_base * (size_t)fw;
                if (cnt == 64) {
                    f4* __restrict__ out4 = (f4*)(out + region);
                    const f4* s4 = (const f4*)fs;
                    #pragma unroll
                    for (int t = lane; t < 16 * fw; t += 64)
                        __builtin_nontemporal_store(s4[t], &out4[t]);
                } else {
                    for (int t = lane; t < cnt * fw; t += 64)
                        out[region + t] = fs[t];
                }
            }
        }
    }
}

extern "C" void kernel_launch(void* const* d_in, const int* in_sizes, int n_in,
                              void* d_out, int out_size, void* d_ws, size_t ws_size,
                              hipStream_t stream) {
    const float* R = (const float*)d_in[0];
    float* out = (float*)d_out;
    int N = in_sizes[0] / 3;

    // Norms in l-outer order: idx = l*(l+1)/2 + m.
    Coefs cf;
    for (int l = 0; l <= LMAX; ++l) {
        for (int m = 0; m <= l; ++m) {
            double fr = 1.0;
            for (int k = l - m + 1; k <= l + m; ++k) fr *= (double)k;
            double norm = sqrt((double)(2 * l + 1) / (4.0 * M_PI) / fr);
            if (m > 0) norm *= sqrt(2.0);
            cf.c[l * (l + 1) / 2 + m] = (float)norm;
        }
    }

    int blocks = (N + 255) / 256;
    sph_kernel<<<blocks, 256, 0, stream>>>(R, out, N, cf);
}